// Round 6
// baseline (689.997 us; speedup 1.0000x reference)
//
#include <hip/hip_runtime.h>
#include <stdint.h>

#define N_BANK 200000
#define N_PAD  212992          // 128 chunks * 1664 cols
#define NQ     2048
#define DIMD   128
#define C_IN   112
#define NCHUNK 128
#define CHUNK_COLS 1664
#define NSTEP  26              // CHUNK_COLS / 64 (64-col steps)
#define NC3    384             // NCHUNK * 3

typedef short v8s __attribute__((ext_vector_type(8)));
typedef float v4f __attribute__((ext_vector_type(4)));

typedef const __attribute__((address_space(1))) uint32_t* gp1_t;
typedef __attribute__((address_space(3))) uint32_t* lp3_t;

__device__ __forceinline__ void async16(const void* g, void* l) {
  __builtin_amdgcn_global_load_lds((gp1_t)g, (lp3_t)l, 16, 0, 0);
}

__device__ __forceinline__ unsigned short f2bf(float f) {
  uint32_t u = __float_as_uint(f);
  u += 0x7fff + ((u >> 16) & 1);   // round-to-nearest-even
  return (unsigned short)(u >> 16);
}

// running top-3 insert: 3 VALU ops via med3
__device__ __forceinline__ void insert3(float& m1, float& m2, float& m3, float v) {
  m3 = __builtin_amdgcn_fmed3f(m2, m3, v);
  m2 = __builtin_amdgcn_fmed3f(m1, m2, v);
  m1 = fmaxf(m1, v);
}

// ---------------- kernel 1: patch embedding (proj + L2 norm -> bf16) --------
// Unswizzled row-major (A is read global->VGPR, no LDS).
__global__ void emb_kernel(const float* __restrict__ fm, const float* __restrict__ pw,
                           unsigned short* __restrict__ embB) {
  int q = blockIdx.x;            // 0..2047, q = b*256 + (h*16+w)
  int b = q >> 8, p = q & 255;
  int tid = threadIdx.x;         // 128 threads = one output dim each
  __shared__ float x[C_IN];
  __shared__ float wsum[2];
  if (tid < C_IN) x[tid] = fm[(b * C_IN + tid) * 256 + p];
  __syncthreads();
  const float* row = pw + tid * C_IN;
  float dot = 0.f;
#pragma unroll
  for (int c = 0; c < C_IN; ++c) dot = fmaf(x[c], row[c], dot);
  float s = dot * dot;
#pragma unroll
  for (int off = 32; off; off >>= 1) s += __shfl_xor(s, off);
  int lane = tid & 63, wv = tid >> 6;
  if (lane == 0) wsum[wv] = s;
  __syncthreads();
  float ss = wsum[0] + wsum[1];
  float scale = 1.f / fmaxf(sqrtf(ss), 1e-12f);
  embB[q * DIMD + tid] = f2bf(dot * scale);
}

// ---------------- kernel 2: bank L2 norm -> bf16, 16B-block swizzled --------
// block j -> j ^ (row&15) within each 256B row (kills LDS bank conflicts).
// float4 loads, 2 rows per wave (lanes 0-31 / 32-63), uint2 stores.
__global__ void bank_kernel(const float* __restrict__ bank, unsigned short* __restrict__ bankB) {
  int tid = threadIdx.x;
  int wv = tid >> 6, lane = tid & 63;
  int half = lane >> 5, l = lane & 31;   // row within pair / lane within row
  uint2* out = (uint2*)bankB;            // 32 uint2 per 256B row
  int j = l >> 1, h = l & 1;             // 16B block, 8B half within
  for (int r0 = (blockIdx.x * 4 + wv) * 2; r0 < N_PAD; r0 += gridDim.x * 8) {
    int r = r0 + half;
    int du2 = ((j ^ (r & 15)) << 1) | h; // swizzled uint2 index in row
    if (r < N_BANK) {
      float4 v = ((const float4*)bank)[r * 32 + l];
      float s = v.x * v.x + v.y * v.y + v.z * v.z + v.w * v.w;
#pragma unroll
      for (int off = 16; off; off >>= 1) s += __shfl_xor(s, off);  // within 32
      float scale = 1.f / fmaxf(sqrtf(s), 1e-12f);
      uint32_t d0 = (uint32_t)f2bf(v.x * scale) | ((uint32_t)f2bf(v.y * scale) << 16);
      uint32_t d1 = (uint32_t)f2bf(v.z * scale) | ((uint32_t)f2bf(v.w * scale) << 16);
      out[r * 32 + du2] = make_uint2(d0, d1);
    } else {
      out[r * 32 + du2] = make_uint2(0u, 0u);
    }
  }
}

// ---------------- kernel 3: fused sims GEMM + running top-3 -----------------
// Restructured K-loop: 2 waves/block, 128 rows/wave (A reg-resident),
// 64-col steps double-buffered in 2x16KB LDS, ONE barrier per step with
// prefetch issued right after the barrier (drain is ~free: loads had the
// whole previous compute phase to land). grid (8 mt, 128 chunks) = 4/CU.
__global__ __launch_bounds__(128, 2)
void sim_top3_kernel(const unsigned short* __restrict__ embB,
                     const unsigned short* __restrict__ bankB,
                     float* __restrict__ partial) {
  int mt = blockIdx.x;           // M tile (256 queries: 2 waves x 128 rows)
  int chunk = blockIdx.y;        // 1664-column bank chunk
  int q0 = mt * 256;
  int tid = threadIdx.x;
  int wv = tid >> 6, lane = tid & 63;
  int g = lane >> 4, c0 = lane & 15;   // frag k-group / col-class

  __shared__ __align__(16) unsigned char lds[2][16384];

  // ---- A fragments direct from global (row-major 256B rows), once ----
  const char* arow = (const char*)embB + (size_t)(q0 + wv * 128 + c0) * 256 + g * 16;
  v8s a[8][4];
#pragma unroll
  for (int fm = 0; fm < 8; ++fm)
#pragma unroll
    for (int k = 0; k < 4; ++k)
      a[fm][k] = *(const v8s*)(arow + fm * 16 * 256 + k * 64);

  float m1[32], m2[32], m3[32];
#pragma unroll
  for (int t = 0; t < 32; ++t) { m1[t] = -1e30f; m2[t] = -1e30f; m3[t] = -1e30f; }

  const char* bbase = (const char*)bankB + (size_t)chunk * CHUNK_COLS * 256;

  // prefetch step 0 into buf 0 (64 rows x 256B = 16KB)
#pragma unroll
  for (int i = 0; i < 8; ++i) {
    int off = i * 2048 + tid * 16;
    async16(bbase + off, &lds[0][0] + off);
  }

  for (int s = 0; s < NSTEP; ++s) {
    __syncthreads();                   // drains vmcnt -> tile s ready; buf(s+1) free
    if (s + 1 < NSTEP) {               // prefetch next tile into other buffer
      const char* bs = bbase + (size_t)(s + 1) * 16384;
      unsigned char* dst = &lds[(s + 1) & 1][0];
#pragma unroll
      for (int i = 0; i < 8; ++i) {
        int off = i * 2048 + tid * 16;
        async16(bs + off, dst + off);
      }
    }
    const unsigned char* buf = &lds[s & 1][0];
#pragma unroll
    for (int fn = 0; fn < 4; ++fn) {
      v8s bf[4];
      int col = fn * 16 + c0;
#pragma unroll
      for (int k = 0; k < 4; ++k)
        bf[k] = *(const v8s*)(buf + col * 256 + (((k * 4 + g) ^ c0) << 4));
#pragma unroll
      for (int fm = 0; fm < 8; ++fm) {
        v4f acc = {0.f, 0.f, 0.f, 0.f};
#pragma unroll
        for (int k = 0; k < 4; ++k)
          acc = __builtin_amdgcn_mfma_f32_16x16x32_bf16(a[fm][k], bf[k], acc, 0, 0, 0);
#pragma unroll
        for (int j = 0; j < 4; ++j)        // C/D: row=g*4+j, col=c0 (within frag)
          insert3(m1[fm * 4 + j], m2[fm * 4 + j], m3[fm * 4 + j], acc[j]);
      }
    }
  }

  // ---- merge top-3 across the 16 col-class lanes (butterfly) ----
#pragma unroll
  for (int mask = 1; mask < 16; mask <<= 1) {
#pragma unroll
    for (int t = 0; t < 32; ++t) {
      float b1 = __shfl_xor(m1[t], mask);
      float b2 = __shfl_xor(m2[t], mask);
      float b3 = __shfl_xor(m3[t], mask);
      insert3(m1[t], m2[t], m3[t], b1);
      insert3(m1[t], m2[t], m3[t], b2);
      insert3(m1[t], m2[t], m3[t], b3);
    }
  }

  if (c0 == 0) {
#pragma unroll
    for (int t = 0; t < 32; ++t) {
      int q = q0 + wv * 128 + (t >> 2) * 16 + g * 4 + (t & 3);
      float* dst = partial + (size_t)q * NC3 + chunk * 3;   // query-major
      dst[0] = m1[t];
      dst[1] = m2[t];
      dst[2] = m3[t];
    }
  }
}

// ---------------- kernel 4a: per-query merge of 384 partials -> patch dist --
// one wave per query; coalesced scan + butterfly top-3 merge
__global__ void merge1_kernel(const float* __restrict__ partial, float* __restrict__ pd) {
  int q = (blockIdx.x * blockDim.x + threadIdx.x) >> 6;
  int lane = threadIdx.x & 63;
  const float* src = partial + (size_t)q * NC3;
  float m1 = -1e30f, m2 = -1e30f, m3 = -1e30f;
  for (int c = lane; c < NC3; c += 64) insert3(m1, m2, m3, src[c]);
#pragma unroll
  for (int mask = 32; mask; mask >>= 1) {
    float b1 = __shfl_xor(m1, mask);
    float b2 = __shfl_xor(m2, mask);
    float b3 = __shfl_xor(m3, mask);
    insert3(m1, m2, m3, b1);
    insert3(m1, m2, m3, b2);
    insert3(m1, m2, m3, b3);
  }
  if (lane == 0) {
    float d1 = sqrtf(fmaxf(2.f - 2.f * m1, 0.f));
    float d2 = sqrtf(fmaxf(2.f - 2.f * m2, 0.f));
    float d3 = sqrtf(fmaxf(2.f - 2.f * m3, 0.f));
    pd[q] = (d1 + d2 + d3) * (1.f / 3.f);
  }
}

// ---------------- kernel 4b: per-image top-8 mean (one wave per image) ------
__global__ void merge2_kernel(const float* __restrict__ pd, float* __restrict__ out) {
  int wv = threadIdx.x >> 6;     // image 0..7
  int lane = threadIdx.x & 63;
  float v[4];
#pragma unroll
  for (int i = 0; i < 4; ++i) v[i] = pd[wv * 256 + i * 64 + lane];
  float sum = 0.f;
  for (int iter = 0; iter < 8; ++iter) {   // k = ceil(256*0.03) = 8
    float lm = v[0]; int li = 0;
#pragma unroll
    for (int i = 1; i < 4; ++i) if (v[i] > lm) { lm = v[i]; li = i; }
    float bm = lm; int bi = (li << 6) | lane;       // global idx, tie-break small idx
#pragma unroll
    for (int off = 32; off; off >>= 1) {
      float ov = __shfl_xor(bm, off);
      int oi = __shfl_xor(bi, off);
      if (ov > bm || (ov == bm && oi < bi)) { bm = ov; bi = oi; }
    }
    sum += bm;
    if ((bi & 63) == lane) v[bi >> 6] = -1e30f;     // exactly one lane clears
  }
  if (lane == 0) out[wv] = sum * (1.f / 8.f);
}

extern "C" void kernel_launch(void* const* d_in, const int* in_sizes, int n_in,
                              void* d_out, int out_size, void* d_ws, size_t ws_size,
                              hipStream_t stream) {
  const float* fm   = (const float*)d_in[0];   // [8,112,16,16]
  const float* pw   = (const float*)d_in[1];   // [128,112]
  const float* bank = (const float*)d_in[2];   // [200000,128]
  float* out = (float*)d_out;                  // [8]

  char* ws = (char*)d_ws;
  unsigned short* bankB = (unsigned short*)ws;                        // 54,525,952 B
  unsigned short* embB  = (unsigned short*)(ws + 54525952);           //    524,288 B
  float* partial        = (float*)(ws + 54525952 + 524288);           //  3,145,728 B
  float* pd             = (float*)(ws + 54525952 + 524288 + 3145728); //      8,192 B

  emb_kernel<<<NQ, 128, 0, stream>>>(fm, pw, embB);
  bank_kernel<<<1024, 256, 0, stream>>>(bank, bankB);
  sim_top3_kernel<<<dim3(8, NCHUNK), 128, 0, stream>>>(embB, bankB, partial);
  merge1_kernel<<<NQ / 4, 256, 0, stream>>>(partial, pd);
  merge2_kernel<<<1, 512, 0, stream>>>(pd, out);
}

// Round 7
// 318.301 us; speedup vs baseline: 2.1678x; 2.1678x over previous
//
#include <hip/hip_runtime.h>
#include <stdint.h>

#define N_BANK 200000
#define N_PAD  212992          // 128 chunks * 1664 cols
#define NQ     2048
#define DIMD   128
#define C_IN   112
#define NCHUNK 128
#define CHUNK_COLS 1664
#define NSTEP  26              // CHUNK_COLS / 64 (64-col steps)
#define NC3    384             // NCHUNK * 3

typedef short v8s __attribute__((ext_vector_type(8)));
typedef float v4f __attribute__((ext_vector_type(4)));

typedef const __attribute__((address_space(1))) uint32_t* gp1_t;
typedef __attribute__((address_space(3))) uint32_t* lp3_t;

__device__ __forceinline__ void async16(const void* g, void* l) {
  __builtin_amdgcn_global_load_lds((gp1_t)g, (lp3_t)l, 16, 0, 0);
}

__device__ __forceinline__ unsigned short f2bf(float f) {
  uint32_t u = __float_as_uint(f);
  u += 0x7fff + ((u >> 16) & 1);   // round-to-nearest-even
  return (unsigned short)(u >> 16);
}

// running top-3 insert: 3 VALU ops via med3
__device__ __forceinline__ void insert3(float& m1, float& m2, float& m3, float v) {
  m3 = __builtin_amdgcn_fmed3f(m2, m3, v);
  m2 = __builtin_amdgcn_fmed3f(m1, m2, v);
  m1 = fmaxf(m1, v);
}

// ---------------- kernel 1: patch embedding (proj + L2 norm -> bf16) --------
__global__ void emb_kernel(const float* __restrict__ fm, const float* __restrict__ pw,
                           unsigned short* __restrict__ embB) {
  int q = blockIdx.x;            // 0..2047, q = b*256 + (h*16+w)
  int b = q >> 8, p = q & 255;
  int tid = threadIdx.x;         // 128 threads = one output dim each
  __shared__ float x[C_IN];
  __shared__ float wsum[2];
  if (tid < C_IN) x[tid] = fm[(b * C_IN + tid) * 256 + p];
  __syncthreads();
  const float* row = pw + tid * C_IN;
  float dot = 0.f;
#pragma unroll
  for (int c = 0; c < C_IN; ++c) dot = fmaf(x[c], row[c], dot);
  float s = dot * dot;
#pragma unroll
  for (int off = 32; off; off >>= 1) s += __shfl_xor(s, off);
  int lane = tid & 63, wv = tid >> 6;
  if (lane == 0) wsum[wv] = s;
  __syncthreads();
  float ss = wsum[0] + wsum[1];
  float scale = 1.f / fmaxf(sqrtf(ss), 1e-12f);
  embB[q * DIMD + tid] = f2bf(dot * scale);
}

// ---------------- kernel 2: bank L2 norm -> bf16, 16B-block swizzled --------
// block j -> j ^ (row&15) within each 256B row (kills LDS bank conflicts).
__global__ void bank_kernel(const float* __restrict__ bank, unsigned short* __restrict__ bankB) {
  int tid = threadIdx.x;
  int wv = tid >> 6, lane = tid & 63;
  int half = lane >> 5, l = lane & 31;   // row within pair / lane within row
  uint2* out = (uint2*)bankB;            // 32 uint2 per 256B row
  int j = l >> 1, h = l & 1;             // 16B block, 8B half within
  for (int r0 = (blockIdx.x * 4 + wv) * 2; r0 < N_PAD; r0 += gridDim.x * 8) {
    int r = r0 + half;
    int du2 = ((j ^ (r & 15)) << 1) | h; // swizzled uint2 index in row
    if (r < N_BANK) {
      float4 v = ((const float4*)bank)[r * 32 + l];
      float s = v.x * v.x + v.y * v.y + v.z * v.z + v.w * v.w;
#pragma unroll
      for (int off = 16; off; off >>= 1) s += __shfl_xor(s, off);  // within 32
      float scale = 1.f / fmaxf(sqrtf(s), 1e-12f);
      uint32_t d0 = (uint32_t)f2bf(v.x * scale) | ((uint32_t)f2bf(v.y * scale) << 16);
      uint32_t d1 = (uint32_t)f2bf(v.z * scale) | ((uint32_t)f2bf(v.w * scale) << 16);
      out[r * 32 + du2] = make_uint2(d0, d1);
    } else {
      out[r * 32 + du2] = make_uint2(0u, 0u);
    }
  }
}

// ---------------- kernel 3: fused sims GEMM + running top-3 -----------------
// 4 waves x 64 rows (R4's proven-no-spill register footprint), 64-col steps
// double-buffered in 2x16KB LDS, ONE barrier per step, prefetch right after
// the barrier. Exact vmax>thr filter skips the 12-op insert ~90% of the time.
// grid (8 mt, 128 chunks) = 1024 blocks.
__global__ __launch_bounds__(256, 2)
void sim_top3_kernel(const unsigned short* __restrict__ embB,
                     const unsigned short* __restrict__ bankB,
                     float* __restrict__ partial) {
  int mt = blockIdx.x;           // M tile (256 queries: 4 waves x 64 rows)
  int chunk = blockIdx.y;        // 1664-column bank chunk
  int q0 = mt * 256;
  int tid = threadIdx.x;
  int wv = tid >> 6, lane = tid & 63;
  int g = lane >> 4, c0 = lane & 15;   // frag k-group / col-class

  __shared__ __align__(16) unsigned char lds[2][16384];

  // ---- A fragments direct from global (row-major 256B rows), once ----
  const char* arow = (const char*)embB + (size_t)(q0 + wv * 64 + c0) * 256 + g * 16;
  v8s a[4][4];
#pragma unroll
  for (int fm = 0; fm < 4; ++fm)
#pragma unroll
    for (int k = 0; k < 4; ++k)
      a[fm][k] = *(const v8s*)(arow + fm * 16 * 256 + k * 64);

  float m1[16], m2[16], m3[16], thr[4];
#pragma unroll
  for (int t = 0; t < 16; ++t) { m1[t] = -1e30f; m2[t] = -1e30f; m3[t] = -1e30f; }
#pragma unroll
  for (int t = 0; t < 4; ++t) thr[t] = -1e30f;

  const char* bbase = (const char*)bankB + (size_t)chunk * CHUNK_COLS * 256;

  // prefetch step 0 into buf 0 (64 bank rows x 256B = 16KB, 256 thr x 16B x 4)
#pragma unroll
  for (int i = 0; i < 4; ++i) {
    int off = i * 4096 + tid * 16;
    async16(bbase + off, &lds[0][0] + off);
  }

  for (int s = 0; s < NSTEP; ++s) {
    __syncthreads();                   // drains vmcnt -> tile s ready (aged 1 phase)
    if (s + 1 < NSTEP) {               // prefetch next tile into other buffer
      const char* bs = bbase + (size_t)(s + 1) * 16384;
      unsigned char* dst = &lds[(s + 1) & 1][0];
#pragma unroll
      for (int i = 0; i < 4; ++i) {
        int off = i * 4096 + tid * 16;
        async16(bs + off, dst + off);
      }
    }
    const unsigned char* buf = &lds[s & 1][0];
#pragma unroll
    for (int fn = 0; fn < 4; ++fn) {
      v8s bf[4];
      int col = fn * 16 + c0;
#pragma unroll
      for (int k = 0; k < 4; ++k)
        bf[k] = *(const v8s*)(buf + col * 256 + (((k * 4 + g) ^ c0) << 4));
#pragma unroll
      for (int fm = 0; fm < 4; ++fm) {
        v4f acc = {0.f, 0.f, 0.f, 0.f};
#pragma unroll
        for (int k = 0; k < 4; ++k)
          acc = __builtin_amdgcn_mfma_f32_16x16x32_bf16(a[fm][k], bf[k], acc, 0, 0, 0);
        // exact filter: nothing can enter top-3 unless vmax > min_j m3 (<= thr cache)
        float vmax = fmaxf(fmaxf(acc[0], acc[1]), fmaxf(acc[2], acc[3]));
        if (vmax > thr[fm]) {
#pragma unroll
          for (int j = 0; j < 4; ++j)      // C/D: row=g*4+j, col=c0 (within frag)
            insert3(m1[fm * 4 + j], m2[fm * 4 + j], m3[fm * 4 + j], acc[j]);
          thr[fm] = fminf(fminf(m3[fm * 4], m3[fm * 4 + 1]),
                          fminf(m3[fm * 4 + 2], m3[fm * 4 + 3]));
        }
      }
    }
  }

  // ---- merge top-3 across the 16 col-class lanes (butterfly) ----
#pragma unroll
  for (int mask = 1; mask < 16; mask <<= 1) {
#pragma unroll
    for (int t = 0; t < 16; ++t) {
      float b1 = __shfl_xor(m1[t], mask);
      float b2 = __shfl_xor(m2[t], mask);
      float b3 = __shfl_xor(m3[t], mask);
      insert3(m1[t], m2[t], m3[t], b1);
      insert3(m1[t], m2[t], m3[t], b2);
      insert3(m1[t], m2[t], m3[t], b3);
    }
  }

  if (c0 == 0) {
#pragma unroll
    for (int t = 0; t < 16; ++t) {
      int q = q0 + wv * 64 + (t >> 2) * 16 + g * 4 + (t & 3);
      float* dst = partial + (size_t)q * NC3 + chunk * 3;   // query-major
      dst[0] = m1[t];
      dst[1] = m2[t];
      dst[2] = m3[t];
    }
  }
}

// ---------------- kernel 4a: per-query merge of 384 partials -> patch dist --
__global__ void merge1_kernel(const float* __restrict__ partial, float* __restrict__ pd) {
  int q = (blockIdx.x * blockDim.x + threadIdx.x) >> 6;
  int lane = threadIdx.x & 63;
  const float* src = partial + (size_t)q * NC3;
  float m1 = -1e30f, m2 = -1e30f, m3 = -1e30f;
  for (int c = lane; c < NC3; c += 64) insert3(m1, m2, m3, src[c]);
#pragma unroll
  for (int mask = 32; mask; mask >>= 1) {
    float b1 = __shfl_xor(m1, mask);
    float b2 = __shfl_xor(m2, mask);
    float b3 = __shfl_xor(m3, mask);
    insert3(m1, m2, m3, b1);
    insert3(m1, m2, m3, b2);
    insert3(m1, m2, m3, b3);
  }
  if (lane == 0) {
    float d1 = sqrtf(fmaxf(2.f - 2.f * m1, 0.f));
    float d2 = sqrtf(fmaxf(2.f - 2.f * m2, 0.f));
    float d3 = sqrtf(fmaxf(2.f - 2.f * m3, 0.f));
    pd[q] = (d1 + d2 + d3) * (1.f / 3.f);
  }
}

// ---------------- kernel 4b: per-image top-8 mean (one wave per image) ------
__global__ void merge2_kernel(const float* __restrict__ pd, float* __restrict__ out) {
  int wv = threadIdx.x >> 6;     // image 0..7
  int lane = threadIdx.x & 63;
  float v[4];
#pragma unroll
  for (int i = 0; i < 4; ++i) v[i] = pd[wv * 256 + i * 64 + lane];
  float sum = 0.f;
  for (int iter = 0; iter < 8; ++iter) {   // k = ceil(256*0.03) = 8
    float lm = v[0]; int li = 0;
#pragma unroll
    for (int i = 1; i < 4; ++i) if (v[i] > lm) { lm = v[i]; li = i; }
    float bm = lm; int bi = (li << 6) | lane;       // global idx, tie-break small idx
#pragma unroll
    for (int off = 32; off; off >>= 1) {
      float ov = __shfl_xor(bm, off);
      int oi = __shfl_xor(bi, off);
      if (ov > bm || (ov == bm && oi < bi)) { bm = ov; bi = oi; }
    }
    sum += bm;
    if ((bi & 63) == lane) v[bi >> 6] = -1e30f;     // exactly one lane clears
  }
  if (lane == 0) out[wv] = sum * (1.f / 8.f);
}

extern "C" void kernel_launch(void* const* d_in, const int* in_sizes, int n_in,
                              void* d_out, int out_size, void* d_ws, size_t ws_size,
                              hipStream_t stream) {
  const float* fm   = (const float*)d_in[0];   // [8,112,16,16]
  const float* pw   = (const float*)d_in[1];   // [128,112]
  const float* bank = (const float*)d_in[2];   // [200000,128]
  float* out = (float*)d_out;                  // [8]

  char* ws = (char*)d_ws;
  unsigned short* bankB = (unsigned short*)ws;                        // 54,525,952 B
  unsigned short* embB  = (unsigned short*)(ws + 54525952);           //    524,288 B
  float* partial        = (float*)(ws + 54525952 + 524288);           //  3,145,728 B
  float* pd             = (float*)(ws + 54525952 + 524288 + 3145728); //      8,192 B

  emb_kernel<<<NQ, 128, 0, stream>>>(fm, pw, embB);
  bank_kernel<<<2048, 256, 0, stream>>>(bank, bankB);
  sim_top3_kernel<<<dim3(8, NCHUNK), 256, 0, stream>>>(embB, bankB, partial);
  merge1_kernel<<<NQ / 4, 256, 0, stream>>>(partial, pd);
  merge2_kernel<<<1, 512, 0, stream>>>(pd, out);
}